// Round 3
// baseline (108.014 us; speedup 1.0000x reference)
//
#include <hip/hip_runtime.h>

// out[b,h,w,dy*9+dx] = leaky_relu( mean_c( prv[b,h,w,c] * nxt[b,h+dy-4,w+dx-4,c] ), 0.1 )
// Banded bf16 MFMA formulation, software-pipelined: register-staged global loads for
// k-step k+1 are issued before the MFMA compute of k-step k (T14 issue-early/write-late).

#define B_ 8
#define H_ 128
#define W_ 128
#define C_ 192
#define ND 9
#define NDISP 81
#define HT 8            // output rows per block (one per wave)
#define WT 32           // output cols per block
#define KS 32           // channels per k-step
#define NK 6            // 192/32
#define BROWS (HT + 8)  // 16 nxt rows staged
#define BCOLS (WT + 8)  // 40 nxt cols staged
#define ACH (4 * HT * WT)        // 1024 16B-chunks of A per kstep
#define BCH (4 * BROWS * BCOLS)  // 2560 16B-chunks of B per kstep
#define AIT (ACH / 512)          // 2 chunks per thread
#define BIT (BCH / 512)          // 5 chunks per thread

typedef short short8 __attribute__((ext_vector_type(8)));
typedef float f32x4 __attribute__((ext_vector_type(4)));

static __device__ __forceinline__ unsigned short f2bf(float f) {
    unsigned u = __float_as_uint(f);
    u += 0x7FFFu + ((u >> 16) & 1u);   // round-to-nearest-even
    return (unsigned short)(u >> 16);
}

static __device__ __forceinline__ short8 cvt8(float4 x, float4 y) {
    short8 v;
    v[0] = (short)f2bf(x.x); v[1] = (short)f2bf(x.y);
    v[2] = (short)f2bf(x.z); v[3] = (short)f2bf(x.w);
    v[4] = (short)f2bf(y.x); v[5] = (short)f2bf(y.y);
    v[6] = (short)f2bf(y.z); v[7] = (short)f2bf(y.w);
    return v;
}

__global__ __launch_bounds__(512, 2)
void cv_mfma(const float* __restrict__ prv, const float* __restrict__ nxt,
             float* __restrict__ out) {
    // LDS: [c-chunk 0..3][pixel][8 bf16] — wave frag reads are contiguous 256B runs, conflict-free.
    __shared__ short8 sA[ACH];   // 16 KB
    __shared__ short8 sB[BCH];   // 40 KB

    const int tid = threadIdx.x;
    const int w0 = blockIdx.x * WT;
    const int h0 = blockIdx.y * HT;
    const int b  = blockIdx.z;

    const int lane = tid & 63;
    const int wid  = tid >> 6;    // 0..7: this wave's output row (h0+wid)
    const int lq = lane & 15;
    const int lc = lane >> 4;

    // ---- hoisted staging addresses (k-step only adds a constant channel offset)
    const float* aptr[AIT];
#pragma unroll
    for (int it = 0; it < AIT; ++it) {
        const int idx = tid + it * 512;
        const int c = idx >> 8;            // / (HT*WT)
        const int r = (idx >> 5) & (HT - 1);
        const int p = idx & (WT - 1);
        aptr[it] = prv + ((size_t)((b * H_ + h0 + r) * W_ + w0 + p)) * C_ + c * 8;
    }
    const float* bptr[BIT];
    bool bok[BIT];
#pragma unroll
    for (int it = 0; it < BIT; ++it) {
        const int idx = tid + it * 512;
        const int c = idx / (BROWS * BCOLS);
        const int rem = idx - c * (BROWS * BCOLS);
        const int r = rem / BCOLS;
        const int pp = rem - r * BCOLS;
        const int gh = h0 - 4 + r;
        const int gw = w0 - 4 + pp;
        bok[it] = ((unsigned)gh < (unsigned)H_) && ((unsigned)gw < (unsigned)W_);
        // pointer computed even when OOB; never dereferenced in that case
        bptr[it] = nxt + (((size_t)b * H_ + gh) * W_ + gw) * C_ + c * 8;
    }

    // ---- register staging buffers; zero-init OOB chunks once (cvt(0)=0 at write time)
    float4 rA[AIT][2];
    float4 rB[BIT][2];
#pragma unroll
    for (int it = 0; it < BIT; ++it) {
        rB[it][0] = make_float4(0.f, 0.f, 0.f, 0.f);
        rB[it][1] = make_float4(0.f, 0.f, 0.f, 0.f);
    }

    // prologue: load k-step 0
#pragma unroll
    for (int it = 0; it < AIT; ++it) {
        rA[it][0] = *(const float4*)(aptr[it]);
        rA[it][1] = *(const float4*)(aptr[it] + 4);
    }
#pragma unroll
    for (int it = 0; it < BIT; ++it) {
        if (bok[it]) {
            rB[it][0] = *(const float4*)(bptr[it]);
            rB[it][1] = *(const float4*)(bptr[it] + 4);
        }
    }

    f32x4 acc[ND][4];
#pragma unroll
    for (int d = 0; d < ND; ++d)
#pragma unroll
        for (int t = 0; t < 4; ++t)
            acc[d][t] = (f32x4){0.f, 0.f, 0.f, 0.f};

    for (int ks = 0; ks < NK; ++ks) {
        if (ks) __syncthreads();   // all waves done reading LDS from previous step

        // ---- write current step's registers to LDS (implicit vmcnt wait on rA/rB)
#pragma unroll
        for (int it = 0; it < AIT; ++it)
            sA[tid + it * 512] = cvt8(rA[it][0], rA[it][1]);
#pragma unroll
        for (int it = 0; it < BIT; ++it)
            sB[tid + it * 512] = cvt8(rB[it][0], rB[it][1]);
        __syncthreads();

        // ---- issue next step's global loads; latency hides under the MFMA phase below
        if (ks + 1 < NK) {
            const int off = (ks + 1) * KS;
#pragma unroll
            for (int it = 0; it < AIT; ++it) {
                rA[it][0] = *(const float4*)(aptr[it] + off);
                rA[it][1] = *(const float4*)(aptr[it] + off + 4);
            }
#pragma unroll
            for (int it = 0; it < BIT; ++it) {
                if (bok[it]) {
                    rB[it][0] = *(const float4*)(bptr[it] + off);
                    rB[it][1] = *(const float4*)(bptr[it] + off + 4);
                }
            }
        }

        // ---- compute: wave `wid` does row h0+wid, all 9 dy, 2 w-tiles x 2 col-tiles
        const short8 a0 = sA[(lc * HT + wid) * WT + lq];
        const short8 a1 = sA[(lc * HT + wid) * WT + 16 + lq];
#pragma unroll
        for (int dy = 0; dy < ND; ++dy) {
            const int base = (lc * BROWS + wid + dy) * BCOLS + lq;
            const short8 b0 = sB[base];        // cols w0-4+q
            const short8 b1 = sB[base + 16];   // cols w0+12+q
            const short8 b2 = sB[base + 32];   // cols w0+28+q
            acc[dy][0] = __builtin_amdgcn_mfma_f32_16x16x32_bf16(a0, b0, acc[dy][0], 0, 0, 0);
            acc[dy][1] = __builtin_amdgcn_mfma_f32_16x16x32_bf16(a0, b1, acc[dy][1], 0, 0, 0);
            acc[dy][2] = __builtin_amdgcn_mfma_f32_16x16x32_bf16(a1, b1, acc[dy][2], 0, 0, 0);
            acc[dy][3] = __builtin_amdgcn_mfma_f32_16x16x32_bf16(a1, b2, acc[dy][3], 0, 0, 0);
        }
    }

    // ---- epilogue: D layout col=lane&15, row=4*(lane>>4)+reg (verified m89/m91)
    // tile pair at w'-offsets -4 / +12: dx = q - r (first) or q - r + 16 (second); exclusive.
    const float inv = 1.0f / (float)C_;
    const int h = h0 + wid;
#pragma unroll
    for (int wt = 0; wt < 2; ++wt) {
#pragma unroll
        for (int rg = 0; rg < 4; ++rg) {
            const int r = 4 * lc + rg;
            const int w = w0 + 16 * wt + r;
            float* o = out + ((size_t)((b * H_ + h) * W_ + w)) * NDISP;
            const int dxa = lq - r;
            const int dxb = dxa + 16;
            if (dxa >= 0 && dxa <= 8) {
#pragma unroll
                for (int dy = 0; dy < ND; ++dy) {
                    const float v = acc[dy][2 * wt][rg] * inv;
                    o[dy * ND + dxa] = v >= 0.f ? v : 0.1f * v;
                }
            }
            if (dxb <= 8) {   // dxb >= 1 always
#pragma unroll
                for (int dy = 0; dy < ND; ++dy) {
                    const float v = acc[dy][2 * wt + 1][rg] * inv;
                    o[dy * ND + dxb] = v >= 0.f ? v : 0.1f * v;
                }
            }
        }
    }
}

extern "C" void kernel_launch(void* const* d_in, const int* in_sizes, int n_in,
                              void* d_out, int out_size, void* d_ws, size_t ws_size,
                              hipStream_t stream) {
    const float* prv = (const float*)d_in[0];
    const float* nxt = (const float*)d_in[1];
    float* out = (float*)d_out;

    dim3 grid(W_ / WT, H_ / HT, B_);   // (4, 16, 8) = 512 blocks
    cv_mfma<<<grid, 512, 0, stream>>>(prv, nxt, out);
}